// Round 13
// baseline (167.600 us; speedup 1.0000x reference)
//
#include <hip/hip_runtime.h>
#include <hip/hip_bf16.h>

typedef short short8 __attribute__((ext_vector_type(8)));
typedef short short4v __attribute__((ext_vector_type(4)));
typedef float float4v __attribute__((ext_vector_type(4)));

#define B_   2
#define L_   1024
#define DIN  512
#define DM   1024
#define DS   16
#define DD   64
#define KER_ 4
#define NROW (B_*L_)     // 2048

// scan geometry: block = (b, 4 d-lanes); 64 chunks x 16 steps = L
#define SD   4
#define SC   64
#define SLC  16
#define SDP  5

__device__ __forceinline__ float silu_f(float v){ return v / (1.f + expf(-v)); }

__device__ __forceinline__ short2 f2bf2(float a, float b) {
  __hip_bfloat162 h = __float22bfloat162_rn(float2{a, b});
  union { __hip_bfloat162 h; short2 s; } u; u.h = h; return u.s;
}
__device__ __forceinline__ short f2bf1(float a) {
  __hip_bfloat16 h = __float2bfloat16(a);
  union { __hip_bfloat16 h; short s; } u; u.h = h; return u.s;
}
__device__ __forceinline__ short8 pack8(const float4& x0, const float4& x1) {
  short2 s0 = f2bf2(x0.x, x0.y), s1 = f2bf2(x0.z, x0.w);
  short2 s2 = f2bf2(x1.x, x1.y), s3 = f2bf2(x1.z, x1.w);
  return short8{ s0.x, s0.y, s1.x, s1.y, s2.x, s2.y, s3.x, s3.y };
}
__device__ __forceinline__ float bf2f(short s) {
  union { unsigned u; float f; } v; v.u = ((unsigned)(unsigned short)s) << 16; return v.f;
}

// ---------------------------------------------------------------------------
// GEMM1: ab[2048,2048](bf16) = seq[2048,512] . Win[2048,512]^T
// BM=BN=64, 256 thr = 4 waves (2x2), wave tile 32x32, BK=32, reg-prefetch.
// ---------------------------------------------------------------------------
__global__ __launch_bounds__(256)
void gemm1_k(const float* __restrict__ seq, const float* __restrict__ Win,
             __hip_bfloat16* __restrict__ ab) {
  __shared__ short As[64 * 40];
  __shared__ short Bs[64 * 40];
  const int tid  = threadIdx.x;
  const int lane = tid & 63;
  const int wave = tid >> 6;
  const int r16  = lane & 15;
  const int quad = lane >> 4;
  const int m0 = blockIdx.y * 64;
  const int n0 = blockIdx.x * 64;
  const int wm = wave & 1, wn = wave >> 1;
  float4v acc[2][2];
#pragma unroll
  for (int i = 0; i < 2; i++)
#pragma unroll
    for (int j = 0; j < 2; j++) acc[i][j] = (float4v){0.f, 0.f, 0.f, 0.f};
  float4 pf0[2], pf1[2];
  auto ldu = [&](int j, int k0) {
    int u = tid + j * 256;
    const float4* p;
    if (u < 256) { int row = u >> 2, q = u & 3;
      p = (const float4*)(seq + (size_t)(m0 + row) * DIN + k0 + q * 8);
    } else { int v = u - 256; int row = v >> 2, q = v & 3;
      p = (const float4*)(Win + (size_t)(n0 + row) * DIN + k0 + q * 8);
    }
    pf0[j] = p[0]; pf1[j] = p[1];
  };
  auto stu = [&](int j) {
    int u = tid + j * 256;
    short8 s = pack8(pf0[j], pf1[j]);
    if (u < 256) { int row = u >> 2, q = u & 3; *(short8*)&As[row * 40 + q * 8] = s; }
    else { int v = u - 256; int row = v >> 2, q = v & 3; *(short8*)&Bs[row * 40 + q * 8] = s; }
  };
  ldu(0, 0); ldu(1, 0);
  for (int k0 = 0; k0 < DIN; k0 += 32) {
    stu(0); stu(1);
    __syncthreads();
    if (k0 + 32 < DIN) { ldu(0, k0 + 32); ldu(1, k0 + 32); }
    short8 afr[2], bfr[2];
#pragma unroll
    for (int mi = 0; mi < 2; mi++)
      afr[mi] = *(const short8*)&As[(wm * 32 + mi * 16 + r16) * 40 + quad * 8];
#pragma unroll
    for (int ni = 0; ni < 2; ni++)
      bfr[ni] = *(const short8*)&Bs[(wn * 32 + ni * 16 + r16) * 40 + quad * 8];
#pragma unroll
    for (int mi = 0; mi < 2; mi++)
#pragma unroll
      for (int ni = 0; ni < 2; ni++)
        acc[mi][ni] = __builtin_amdgcn_mfma_f32_16x16x32_bf16(afr[mi], bfr[ni], acc[mi][ni], 0, 0, 0);
    __syncthreads();
  }
#pragma unroll
  for (int mi = 0; mi < 2; mi++)
#pragma unroll
    for (int ni = 0; ni < 2; ni++) {
      int gn = n0 + wn * 32 + ni * 16 + r16;
#pragma unroll
      for (int r = 0; r < 4; r++) {
        int gm = m0 + wm * 32 + mi * 16 + quad * 4 + r;
        ab[(size_t)gm * (2 * DM) + gn] = __float2bfloat16(acc[mi][ni][r]);
      }
    }
}

// ---------------------------------------------------------------------------
// convT: for d<DM: xT[d][n] = silu(conv(ab)) (f32); for d>=DM: gT[d-DM][n] =
// ab[n][d] (bf16 transpose). Coalesced via LDS tile (67 rows halo).
// ---------------------------------------------------------------------------
__global__ __launch_bounds__(256)
void convT_k(const __hip_bfloat16* __restrict__ ab, const float* __restrict__ cw,
             const float* __restrict__ cb, float* __restrict__ xt,
             short* __restrict__ gt) {
  __shared__ short tile[67 * 74];
  const int n0 = blockIdx.x * 64;
  const int d0 = blockIdx.y * 64;          // 0..2047
  const int l0 = n0 & (L_ - 1);
  for (int u = threadIdx.x; u < 67 * 8; u += 256) {
    int r = u >> 3, c8 = u & 7;
    int l = l0 - 3 + r;
    short8 v = short8{0, 0, 0, 0, 0, 0, 0, 0};
    if (l >= 0 && r < 67)
      v = *(const short8*)(ab + (size_t)(n0 - l0 + l) * (2 * DM) + d0 + c8 * 8);
    *(short8*)&tile[r * 74 + c8 * 8] = v;
  }
  __syncthreads();
  const int i  = threadIdx.x & 63;
  const int dl = threadIdx.x >> 6;         // 0..3
  if (d0 < DM) {
#pragma unroll 4
    for (int p = 0; p < 16; p++) {
      int dc = p * 4 + dl;
      int d  = d0 + dc;
      float4 w = *(const float4*)(cw + d * 4);
      float a = cb[d];
      a += bf2f(tile[(i + 0) * 74 + dc]) * w.x;
      a += bf2f(tile[(i + 1) * 74 + dc]) * w.y;
      a += bf2f(tile[(i + 2) * 74 + dc]) * w.z;
      a += bf2f(tile[(i + 3) * 74 + dc]) * w.w;
      xt[(size_t)d * NROW + n0 + i] = silu_f(a);
    }
  } else {
#pragma unroll 4
    for (int p = 0; p < 16; p++) {
      int dc = p * 4 + dl;
      gt[(size_t)(d0 - DM + dc) * NROW + n0 + i] = tile[(i + 3) * 74 + dc];
    }
  }
}

// ---------------------------------------------------------------------------
// proj: pall[2048,96] += x . [WB|WC|WD1]^T, x = silu(conv(ab)) in staging.
// split-K x8 (4 iters), BM=64, BN=96, 256 thr, atomicAdd (pall pre-zeroed).
// ---------------------------------------------------------------------------
__global__ __launch_bounds__(256)
void proj_k(const __hip_bfloat16* __restrict__ ab, const float* __restrict__ WB,
            const float* __restrict__ WC, const float* __restrict__ WD1,
            const float* __restrict__ cw, const float* __restrict__ cb,
            float* __restrict__ pall) {
  __shared__ short As[64 * 40];
  __shared__ short Bs[96 * 40];
  const int tid  = threadIdx.x;
  const int lane = tid & 63;
  const int wave = tid >> 6;
  const int r16  = lane & 15;
  const int quad = lane >> 4;
  const int m0   = blockIdx.y * 64;
  const int kbeg = blockIdx.z * 128;
  float4v acc[6];
#pragma unroll
  for (int i = 0; i < 6; i++) acc[i] = (float4v){0.f, 0.f, 0.f, 0.f};

  short8 ta[KER_];
  float4 pf0[2], pf1[2];
  const int arow = tid >> 2, aq = tid & 3;
  const int an = m0 + arow, al = an & (L_ - 1), abq = an >> 10;

  auto ldu_a = [&](int k0) {
#pragma unroll
    for (int t = 0; t < KER_; t++) {
      int ll = al - (KER_ - 1) + t;
      if (ll >= 0)
        ta[t] = *(const short8*)(ab + (size_t)(abq * L_ + ll) * (2 * DM) + k0 + aq * 8);
      else
        ta[t] = short8{0, 0, 0, 0, 0, 0, 0, 0};
    }
  };
  auto stu_a = [&](int k0) {
    float r8[8];
#pragma unroll
    for (int e = 0; e < 8; e++) {
      int d = k0 + aq * 8 + e;
      float4 w = *(const float4*)(cw + d * 4);
      float a = cb[d];
      a += bf2f(ta[0][e]) * w.x;
      a += bf2f(ta[1][e]) * w.y;
      a += bf2f(ta[2][e]) * w.z;
      a += bf2f(ta[3][e]) * w.w;
      r8[e] = silu_f(a);
    }
    *(short8*)&As[arow * 40 + aq * 8] =
        pack8(float4{r8[0], r8[1], r8[2], r8[3]}, float4{r8[4], r8[5], r8[6], r8[7]});
  };
  auto ldu_b = [&](int j, int k0) {
    int u = tid + j * 256;
    if (u >= 640) return;
    int v = u - 256, row = v >> 2, q = v & 3;
    const float* bp = (row < 16) ? (WB + (size_t)row * DM)
                    : (row < 32) ? (WC + (size_t)(row - 16) * DM)
                                 : (WD1 + (size_t)(row - 32) * DM);
    const float4* p = (const float4*)(bp + k0 + q * 8);
    pf0[j - 1] = p[0]; pf1[j - 1] = p[1];
  };
  auto stu_b = [&](int j) {
    int u = tid + j * 256;
    if (u >= 640) return;
    int v = u - 256, row = v >> 2, q = v & 3;
    *(short8*)&Bs[row * 40 + q * 8] = pack8(pf0[j - 1], pf1[j - 1]);
  };

  ldu_a(kbeg); ldu_b(1, kbeg); ldu_b(2, kbeg);
  for (int k0 = kbeg; k0 < kbeg + 128; k0 += 32) {
    stu_a(k0); stu_b(1); stu_b(2);
    __syncthreads();
    if (k0 + 32 < kbeg + 128) { ldu_a(k0 + 32); ldu_b(1, k0 + 32); ldu_b(2, k0 + 32); }
    short8 afr = *(const short8*)&As[(wave * 16 + r16) * 40 + quad * 8];
#pragma unroll
    for (int ni = 0; ni < 6; ni++) {
      short8 bfr = *(const short8*)&Bs[(ni * 16 + r16) * 40 + quad * 8];
      acc[ni] = __builtin_amdgcn_mfma_f32_16x16x32_bf16(afr, bfr, acc[ni], 0, 0, 0);
    }
    __syncthreads();
  }
#pragma unroll
  for (int ni = 0; ni < 6; ni++) {
    int gn = ni * 16 + r16;
#pragma unroll
    for (int r = 0; r < 4; r++) {
      int gm = m0 + wave * 16 + quad * 4 + r;
      atomicAdd(&pall[(size_t)gm * 96 + gn], acc[ni][r]);
    }
  }
}

// ---------------------------------------------------------------------------
// delta: dltT[1024,2048] = softplus(t1 . WD2^T + Dv)^T  (transposed store)
// ---------------------------------------------------------------------------
__global__ __launch_bounds__(256)
void delta_k(const float* __restrict__ t1, const float* __restrict__ WD2,
             const float* __restrict__ Dv, float* __restrict__ dltT) {
  __shared__ short As[64 * 40];
  __shared__ short Bs[64 * 40];
  const int tid  = threadIdx.x;
  const int lane = tid & 63;
  const int wave = tid >> 6;
  const int r16  = lane & 15;
  const int quad = lane >> 4;
  const int m0 = blockIdx.y * 64;
  const int n0 = blockIdx.x * 64;
  const int wm = wave & 1, wn = wave >> 1;
  float4v acc[2][2];
#pragma unroll
  for (int i = 0; i < 2; i++)
#pragma unroll
    for (int j = 0; j < 2; j++) acc[i][j] = (float4v){0.f, 0.f, 0.f, 0.f};
  float4 pf0[2], pf1[2];
  auto ldu = [&](int j, int k0) {
    int u = tid + j * 256;
    const float4* p;
    if (u < 256) { int row = u >> 2, q = u & 3;
      p = (const float4*)(t1 + (size_t)(m0 + row) * 96 + k0 + q * 8);
    } else { int v = u - 256; int row = v >> 2, q = v & 3;
      p = (const float4*)(WD2 + (size_t)(n0 + row) * DD + k0 + q * 8);
    }
    pf0[j] = p[0]; pf1[j] = p[1];
  };
  auto stu = [&](int j) {
    int u = tid + j * 256;
    short8 s = pack8(pf0[j], pf1[j]);
    if (u < 256) { int row = u >> 2, q = u & 3; *(short8*)&As[row * 40 + q * 8] = s; }
    else { int v = u - 256; int row = v >> 2, q = v & 3; *(short8*)&Bs[row * 40 + q * 8] = s; }
  };
  ldu(0, 0); ldu(1, 0);
  for (int k0 = 0; k0 < DD; k0 += 32) {
    stu(0); stu(1);
    __syncthreads();
    if (k0 + 32 < DD) { ldu(0, k0 + 32); ldu(1, k0 + 32); }
    short8 afr[2], bfr[2];
#pragma unroll
    for (int mi = 0; mi < 2; mi++)
      afr[mi] = *(const short8*)&As[(wm * 32 + mi * 16 + r16) * 40 + quad * 8];
#pragma unroll
    for (int ni = 0; ni < 2; ni++)
      bfr[ni] = *(const short8*)&Bs[(wn * 32 + ni * 16 + r16) * 40 + quad * 8];
#pragma unroll
    for (int mi = 0; mi < 2; mi++)
#pragma unroll
      for (int ni = 0; ni < 2; ni++)
        acc[mi][ni] = __builtin_amdgcn_mfma_f32_16x16x32_bf16(afr[mi], bfr[ni], acc[mi][ni], 0, 0, 0);
    __syncthreads();
  }
#pragma unroll
  for (int mi = 0; mi < 2; mi++)
#pragma unroll
    for (int ni = 0; ni < 2; ni++) {
      int gn = n0 + wn * 32 + ni * 16 + r16;
      float dvn = Dv[gn];
#pragma unroll
      for (int r = 0; r < 4; r++) {
        int gm = m0 + wm * 32 + mi * 16 + quad * 4 + r;
        float v = acc[mi][ni][r] + dvn;
        v = fmaxf(v, 0.f) + log1pf(expf(-fabsf(v)));   // stable softplus
        dltT[(size_t)gn * NROW + gm] = v;              // transposed, 16B runs
      }
    }
}

// ---------------------------------------------------------------------------
// Fused selective scan, transposed operands, quad-batched loads (R12-proven).
// sout now stored bf16 (RNE at store == gemm2's old staging convert, so the
// final output is bit-identical).
// ---------------------------------------------------------------------------
__global__ __launch_bounds__(256)
void scan_fused_k(const float* __restrict__ xt, const float* __restrict__ dltT,
                  const float* __restrict__ pall, const float* __restrict__ A,
                  const float* __restrict__ Dv, const short* __restrict__ gt,
                  short* __restrict__ soutb) {
  __shared__ float Pl[SC][DS][SDP];
  __shared__ float Hl[SC][DS][SDP];
  const int blk = blockIdx.x;
  const int b   = blk >> 8;                // DM/SD = 256 blocks per batch
  const int d0  = (blk & 255) * SD;
  const int dd  = threadIdx.x & (SD - 1);
  const int c   = threadIdx.x >> 2;        // 0..63
  const int d   = d0 + dd;

  float e[DS];
#pragma unroll
  for (int s = 0; s < DS; s++) e[s] = expf(-A[d * DS + s]);
  const int nbase = b * L_ + c * SLC;
  const float* xrow = xt   + (size_t)d * NROW;
  const float* drow = dltT + (size_t)d * NROW;
  const short* grow = gt   + (size_t)d * NROW;

  // ---- phase A: local chunk scan, quad-batched ------------------------
  float h[DS], p[DS];
#pragma unroll
  for (int s = 0; s < DS; s++) { h[s] = 0.f; p[s] = 1.f; }
#pragma unroll
  for (int q = 0; q < SLC / 4; q++) {
    const int n = nbase + q * 4;
    float4 x4 = *(const float4*)(xrow + n);
    float4 d4 = *(const float4*)(drow + n);
    float4 bq[4][4];
#pragma unroll
    for (int t = 0; t < 4; t++) {
      const float4* pp = (const float4*)(pall + (size_t)(n + t) * 96);
      bq[t][0] = pp[0]; bq[t][1] = pp[1]; bq[t][2] = pp[2]; bq[t][3] = pp[3];
    }
#pragma unroll
    for (int t = 0; t < 4; t++) {
      float dl = (&d4.x)[t], xv = (&x4.x)[t];
      float dx = dl * xv;
      float bmv[DS] = { bq[t][0].x, bq[t][0].y, bq[t][0].z, bq[t][0].w,
                        bq[t][1].x, bq[t][1].y, bq[t][1].z, bq[t][1].w,
                        bq[t][2].x, bq[t][2].y, bq[t][2].z, bq[t][2].w,
                        bq[t][3].x, bq[t][3].y, bq[t][3].z, bq[t][3].w };
#pragma unroll
      for (int s = 0; s < DS; s++) {
        float a_ = e[s] * dl;
        h[s] = a_ * h[s] + bmv[s] * dx;
        p[s] *= a_;
      }
    }
  }
#pragma unroll
  for (int s = 0; s < DS; s++) { Pl[c][s][dd] = p[s]; Hl[c][s][dd] = h[s]; }
  __syncthreads();

  // ---- phase B: serial combine of 64 chunk carries --------------------
  if (threadIdx.x < DS * SD) {
    int s2  = threadIdx.x >> 2;
    int dd2 = threadIdx.x & (SD - 1);
    float H = 0.f;
    for (int c2 = 0; c2 < SC; c2++) {
      float pp = Pl[c2][s2][dd2];
      float hh = Hl[c2][s2][dd2];
      Pl[c2][s2][dd2] = H;
      H = pp * H + hh;
    }
  }
  __syncthreads();

  // ---- phase C: replay with fused epilogue, quad-batched --------------
#pragma unroll
  for (int s = 0; s < DS; s++) h[s] = Pl[c][s][dd];
  float Dd = Dv[d];
#pragma unroll
  for (int q = 0; q < SLC / 4; q++) {
    const int n = nbase + q * 4;
    float4 x4 = *(const float4*)(xrow + n);
    float4 d4 = *(const float4*)(drow + n);
    short4v g4 = *(const short4v*)(grow + n);
    float4 bq[4][4], cq[4][4];
#pragma unroll
    for (int t = 0; t < 4; t++) {
      const float4* pp = (const float4*)(pall + (size_t)(n + t) * 96);
      bq[t][0] = pp[0]; bq[t][1] = pp[1]; bq[t][2] = pp[2]; bq[t][3] = pp[3];
      cq[t][0] = pp[4]; cq[t][1] = pp[5]; cq[t][2] = pp[6]; cq[t][3] = pp[7];
    }
#pragma unroll
    for (int t = 0; t < 4; t++) {
      float dl = (&d4.x)[t], xv = (&x4.x)[t];
      float dx = dl * xv;
      float bmv[DS] = { bq[t][0].x, bq[t][0].y, bq[t][0].z, bq[t][0].w,
                        bq[t][1].x, bq[t][1].y, bq[t][1].z, bq[t][1].w,
                        bq[t][2].x, bq[t][2].y, bq[t][2].z, bq[t][2].w,
                        bq[t][3].x, bq[t][3].y, bq[t][3].z, bq[t][3].w };
      float cmv[DS] = { cq[t][0].x, cq[t][0].y, cq[t][0].z, cq[t][0].w,
                        cq[t][1].x, cq[t][1].y, cq[t][1].z, cq[t][1].w,
                        cq[t][2].x, cq[t][2].y, cq[t][2].z, cq[t][2].w,
                        cq[t][3].x, cq[t][3].y, cq[t][3].z, cq[t][3].w };
      float y = 0.f;
#pragma unroll
      for (int s = 0; s < DS; s++) {
        h[s] = e[s] * dl * h[s] + bmv[s] * dx;
        y += h[s] * cmv[s];
      }
      y += Dd * xv;
      float g = bf2f(g4[t]);
      soutb[(size_t)(n + t) * DM + d] = f2bf1(y * silu_f(g));
    }
  }
}

// ---------------------------------------------------------------------------
// GEMM2: out[2048,512] = sout(bf16)[2048,1024] . Wout[512,1024]^T
// BM=64, BN=32 -> grid (16,32) = 512 blocks (2 blocks/CU for TLP).
// 256 thr = 4 waves (2x2), wave tile 32x16. A staged with NO convert (bf16).
// ---------------------------------------------------------------------------
__global__ __launch_bounds__(256)
void gemm2_k(const short* __restrict__ soutb, const float* __restrict__ Wout,
             float* __restrict__ out) {
  __shared__ short As[64 * 40];
  __shared__ short Bs[32 * 40];
  const int tid  = threadIdx.x;
  const int lane = tid & 63;
  const int wave = tid >> 6;
  const int r16  = lane & 15;
  const int quad = lane >> 4;
  const int m0 = blockIdx.y * 64;
  const int n0 = blockIdx.x * 32;
  const int wm = wave & 1, wn = wave >> 1;
  float4v acc[2];
  acc[0] = (float4v){0.f, 0.f, 0.f, 0.f};
  acc[1] = (float4v){0.f, 0.f, 0.f, 0.f};
  short8 pa;              // A unit (bf16 direct)
  float4 pf0, pf1;        // B unit
  auto ldu = [&](int k0) {
    if (tid < 256) {      // A: 64 rows x 4 q-units
      int row = tid >> 2, q = tid & 3;
      pa = *(const short8*)(soutb + (size_t)(m0 + row) * DM + k0 + q * 8);
    }
    if (tid < 128) {      // B: 32 rows x 4 q-units (first 128 threads also load B)
      int row = tid >> 2, q = tid & 3;
      const float4* p = (const float4*)(Wout + (size_t)(n0 + row) * DM + k0 + q * 8);
      pf0 = p[0]; pf1 = p[1];
    }
  };
  auto stu = [&]() {
    { int row = tid >> 2, q = tid & 3; *(short8*)&As[row * 40 + q * 8] = pa; }
    if (tid < 128) { int row = tid >> 2, q = tid & 3; *(short8*)&Bs[row * 40 + q * 8] = pack8(pf0, pf1); }
  };
  ldu(0);
  for (int k0 = 0; k0 < DM; k0 += 32) {
    stu();
    __syncthreads();
    if (k0 + 32 < DM) ldu(k0 + 32);
    short8 afr[2], bfr;
    afr[0] = *(const short8*)&As[(wm * 32 + r16) * 40 + quad * 8];
    afr[1] = *(const short8*)&As[(wm * 32 + 16 + r16) * 40 + quad * 8];
    bfr    = *(const short8*)&Bs[(wn * 16 + r16) * 40 + quad * 8];
    acc[0] = __builtin_amdgcn_mfma_f32_16x16x32_bf16(afr[0], bfr, acc[0], 0, 0, 0);
    acc[1] = __builtin_amdgcn_mfma_f32_16x16x32_bf16(afr[1], bfr, acc[1], 0, 0, 0);
    __syncthreads();
  }
#pragma unroll
  for (int mi = 0; mi < 2; mi++)
#pragma unroll
    for (int r = 0; r < 4; r++)
      out[(size_t)(m0 + wm * 32 + mi * 16 + quad * 4 + r) * DIN + n0 + wn * 16 + r16] = acc[mi][r];
}

// ---------------------------------------------------------------------------
extern "C" void kernel_launch(void* const* d_in, const int* in_sizes, int n_in,
                              void* d_out, int out_size, void* d_ws, size_t ws_size,
                              hipStream_t stream) {
  const float* seq  = (const float*)d_in[0];
  const float* Win  = (const float*)d_in[1];
  const float* Wout = (const float*)d_in[2];
  const float* WB   = (const float*)d_in[3];
  const float* WC   = (const float*)d_in[4];
  const float* WD1  = (const float*)d_in[5];
  const float* WD2  = (const float*)d_in[6];
  const float* cw   = (const float*)d_in[7];
  const float* cb   = (const float*)d_in[8];
  const float* A    = (const float*)d_in[9];
  const float* Dv   = (const float*)d_in[10];
  float* out = (float*)d_out;

  float* ws = (float*)d_ws;
  __hip_bfloat16* ab = (__hip_bfloat16*)ws;       // 2048*2048 bf16
  float* xt   = ws   + 2097152;                   // 1024*2048 f32  (x transposed)
  short* gt   = (short*)(xt + 2097152);           // 1024*2048 bf16 (gate transposed)
  float* dltT = (float*)(gt + 2097152);           // 1024*2048 f32  (delta transposed)
  float* pall = dltT + 2097152;                   // 2048*96 f32 (Bm|Cm|t1)
  short* soutb = (short*)(pall + 196608);         // 2048*1024 bf16
  // total ~35 MB (proven budget 47)
  float* t1   = pall + 32;                        // t1 rows at col 32 (ld 96)

  hipMemsetAsync(pall, 0, (size_t)NROW * 96 * 4, stream);
  gemm1_k<<<dim3(32, 32), 256, 0, stream>>>(seq, Win, ab);
  convT_k<<<dim3(NROW / 64, (2 * DM) / 64), 256, 0, stream>>>(ab, cw, cb, xt, gt);
  proj_k<<<dim3(1, 32, 8), 256, 0, stream>>>(ab, WB, WC, WD1, cw, cb, pall);
  delta_k<<<dim3(16, 32), 256, 0, stream>>>(t1, WD2, Dv, dltT);
  scan_fused_k<<<B_ * (DM / SD), 256, 0, stream>>>(xt, dltT, pall, A, Dv, gt, soutb);
  gemm2_k<<<dim3(16, 32), 256, 0, stream>>>(soutb, Wout, out);
}

// Round 14
// 159.765 us; speedup vs baseline: 1.0490x; 1.0490x over previous
//
#include <hip/hip_runtime.h>
#include <hip/hip_bf16.h>

typedef short short8 __attribute__((ext_vector_type(8)));
typedef short short4v __attribute__((ext_vector_type(4)));
typedef float float4v __attribute__((ext_vector_type(4)));

#define B_   2
#define L_   1024
#define DIN  512
#define DM   1024
#define DS   16
#define DD   64
#define KER_ 4
#define NROW (B_*L_)     // 2048

// scan geometry: block = (b, 4 d-lanes); 64 chunks x 16 steps = L
#define SD   4
#define SC   64
#define SLC  16
#define SDP  5

__device__ __forceinline__ float silu_f(float v){ return v / (1.f + expf(-v)); }

__device__ __forceinline__ short2 f2bf2(float a, float b) {
  __hip_bfloat162 h = __float22bfloat162_rn(float2{a, b});
  union { __hip_bfloat162 h; short2 s; } u; u.h = h; return u.s;
}
__device__ __forceinline__ short f2bf1(float a) {
  __hip_bfloat16 h = __float2bfloat16(a);
  union { __hip_bfloat16 h; short s; } u; u.h = h; return u.s;
}
__device__ __forceinline__ short8 pack8(const float4& x0, const float4& x1) {
  short2 s0 = f2bf2(x0.x, x0.y), s1 = f2bf2(x0.z, x0.w);
  short2 s2 = f2bf2(x1.x, x1.y), s3 = f2bf2(x1.z, x1.w);
  return short8{ s0.x, s0.y, s1.x, s1.y, s2.x, s2.y, s3.x, s3.y };
}
__device__ __forceinline__ float bf2f(short s) {
  union { unsigned u; float f; } v; v.u = ((unsigned)(unsigned short)s) << 16; return v.f;
}

// ---------------------------------------------------------------------------
// GEMM1: ab[2048,2048](bf16) = seq[2048,512] . Win[2048,512]^T
// BM=BN=64, 256 thr = 4 waves (2x2), wave tile 32x32, BK=32, reg-prefetch.
// Also zeroes pall (disjoint from own writes; stream order covers proj).
// ---------------------------------------------------------------------------
__global__ __launch_bounds__(256)
void gemm1_k(const float* __restrict__ seq, const float* __restrict__ Win,
             __hip_bfloat16* __restrict__ ab, float* __restrict__ pall) {
  __shared__ short As[64 * 40];
  __shared__ short Bs[64 * 40];
  const int tid  = threadIdx.x;
  // fold-in: zero pall (196608 floats over 1024 blocks x 256 thr)
  {
    int zi = (blockIdx.y * 32 + blockIdx.x) * 256 + tid;
    if (zi < NROW * 96) pall[zi] = 0.f;
  }
  const int lane = tid & 63;
  const int wave = tid >> 6;
  const int r16  = lane & 15;
  const int quad = lane >> 4;
  const int m0 = blockIdx.y * 64;
  const int n0 = blockIdx.x * 64;
  const int wm = wave & 1, wn = wave >> 1;
  float4v acc[2][2];
#pragma unroll
  for (int i = 0; i < 2; i++)
#pragma unroll
    for (int j = 0; j < 2; j++) acc[i][j] = (float4v){0.f, 0.f, 0.f, 0.f};
  float4 pf0[2], pf1[2];
  auto ldu = [&](int j, int k0) {
    int u = tid + j * 256;
    const float4* p;
    if (u < 256) { int row = u >> 2, q = u & 3;
      p = (const float4*)(seq + (size_t)(m0 + row) * DIN + k0 + q * 8);
    } else { int v = u - 256; int row = v >> 2, q = v & 3;
      p = (const float4*)(Win + (size_t)(n0 + row) * DIN + k0 + q * 8);
    }
    pf0[j] = p[0]; pf1[j] = p[1];
  };
  auto stu = [&](int j) {
    int u = tid + j * 256;
    short8 s = pack8(pf0[j], pf1[j]);
    if (u < 256) { int row = u >> 2, q = u & 3; *(short8*)&As[row * 40 + q * 8] = s; }
    else { int v = u - 256; int row = v >> 2, q = v & 3; *(short8*)&Bs[row * 40 + q * 8] = s; }
  };
  ldu(0, 0); ldu(1, 0);
  for (int k0 = 0; k0 < DIN; k0 += 32) {
    stu(0); stu(1);
    __syncthreads();
    if (k0 + 32 < DIN) { ldu(0, k0 + 32); ldu(1, k0 + 32); }
    short8 afr[2], bfr[2];
#pragma unroll
    for (int mi = 0; mi < 2; mi++)
      afr[mi] = *(const short8*)&As[(wm * 32 + mi * 16 + r16) * 40 + quad * 8];
#pragma unroll
    for (int ni = 0; ni < 2; ni++)
      bfr[ni] = *(const short8*)&Bs[(wn * 32 + ni * 16 + r16) * 40 + quad * 8];
#pragma unroll
    for (int mi = 0; mi < 2; mi++)
#pragma unroll
      for (int ni = 0; ni < 2; ni++)
        acc[mi][ni] = __builtin_amdgcn_mfma_f32_16x16x32_bf16(afr[mi], bfr[ni], acc[mi][ni], 0, 0, 0);
    __syncthreads();
  }
#pragma unroll
  for (int mi = 0; mi < 2; mi++)
#pragma unroll
    for (int ni = 0; ni < 2; ni++) {
      int gn = n0 + wn * 32 + ni * 16 + r16;
#pragma unroll
      for (int r = 0; r < 4; r++) {
        int gm = m0 + wm * 32 + mi * 16 + quad * 4 + r;
        ab[(size_t)gm * (2 * DM) + gn] = __float2bfloat16(acc[mi][ni][r]);
      }
    }
}

// ---------------------------------------------------------------------------
// convT + proj merged (independent consumers of ab; block-range split).
// blk < 1024: convT tile -> xT (f32, silu(conv)) / gT (bf16 gate transpose).
// blk >= 1024: proj split-K block -> pall atomicAdd (pall zeroed by gemm1).
// ---------------------------------------------------------------------------
__global__ __launch_bounds__(256)
void convproj_k(const __hip_bfloat16* __restrict__ ab, const float* __restrict__ cw,
                const float* __restrict__ cb, const float* __restrict__ WB,
                const float* __restrict__ WC, const float* __restrict__ WD1,
                float* __restrict__ xt, short* __restrict__ gt,
                float* __restrict__ pall) {
  __shared__ char smraw[12800];
  const int blk = blockIdx.x;
  const int tid = threadIdx.x;

  if (blk < 1024) {
    // ---------------- convT (verbatim R13 body) -------------------------
    short* tile = (short*)smraw;               // 67*74 shorts = 9916 B
    const int n0 = (blk & 31) * 64;
    const int d0 = (blk >> 5) * 64;            // 0..2047
    const int l0 = n0 & (L_ - 1);
    for (int u = tid; u < 67 * 8; u += 256) {
      int r = u >> 3, c8 = u & 7;
      int l = l0 - 3 + r;
      short8 v = short8{0, 0, 0, 0, 0, 0, 0, 0};
      if (l >= 0 && r < 67)
        v = *(const short8*)(ab + (size_t)(n0 - l0 + l) * (2 * DM) + d0 + c8 * 8);
      *(short8*)&tile[r * 74 + c8 * 8] = v;
    }
    __syncthreads();
    const int i  = tid & 63;
    const int dl = tid >> 6;                   // 0..3
    if (d0 < DM) {
#pragma unroll 4
      for (int p = 0; p < 16; p++) {
        int dc = p * 4 + dl;
        int d  = d0 + dc;
        float4 w = *(const float4*)(cw + d * 4);
        float a = cb[d];
        a += bf2f(tile[(i + 0) * 74 + dc]) * w.x;
        a += bf2f(tile[(i + 1) * 74 + dc]) * w.y;
        a += bf2f(tile[(i + 2) * 74 + dc]) * w.z;
        a += bf2f(tile[(i + 3) * 74 + dc]) * w.w;
        xt[(size_t)d * NROW + n0 + i] = silu_f(a);
      }
    } else {
#pragma unroll 4
      for (int p = 0; p < 16; p++) {
        int dc = p * 4 + dl;
        gt[(size_t)(d0 - DM + dc) * NROW + n0 + i] = tile[(i + 3) * 74 + dc];
      }
    }
    return;
  }

  // ---------------- proj (verbatim R13 body) ----------------------------
  short* As = (short*)smraw;                   // 64*40
  short* Bs = As + 64 * 40;                    // 96*40  (total 12800 B)
  const int b2   = blk - 1024;                 // 0..255
  const int lane = tid & 63;
  const int wave = tid >> 6;
  const int r16  = lane & 15;
  const int quad = lane >> 4;
  const int m0   = (b2 & 31) * 64;
  const int kbeg = (b2 >> 5) * 128;
  float4v acc[6];
#pragma unroll
  for (int i = 0; i < 6; i++) acc[i] = (float4v){0.f, 0.f, 0.f, 0.f};

  short8 ta[KER_];
  float4 pf0[2], pf1[2];
  const int arow = tid >> 2, aq = tid & 3;
  const int an = m0 + arow, al = an & (L_ - 1), abq = an >> 10;

  auto ldu_a = [&](int k0) {
#pragma unroll
    for (int t = 0; t < KER_; t++) {
      int ll = al - (KER_ - 1) + t;
      if (ll >= 0)
        ta[t] = *(const short8*)(ab + (size_t)(abq * L_ + ll) * (2 * DM) + k0 + aq * 8);
      else
        ta[t] = short8{0, 0, 0, 0, 0, 0, 0, 0};
    }
  };
  auto stu_a = [&](int k0) {
    float r8[8];
#pragma unroll
    for (int e = 0; e < 8; e++) {
      int d = k0 + aq * 8 + e;
      float4 w = *(const float4*)(cw + d * 4);
      float a = cb[d];
      a += bf2f(ta[0][e]) * w.x;
      a += bf2f(ta[1][e]) * w.y;
      a += bf2f(ta[2][e]) * w.z;
      a += bf2f(ta[3][e]) * w.w;
      r8[e] = silu_f(a);
    }
    *(short8*)&As[arow * 40 + aq * 8] =
        pack8(float4{r8[0], r8[1], r8[2], r8[3]}, float4{r8[4], r8[5], r8[6], r8[7]});
  };
  auto ldu_b = [&](int j, int k0) {
    int u = tid + j * 256;
    if (u >= 640) return;
    int v = u - 256, row = v >> 2, q = v & 3;
    const float* bp = (row < 16) ? (WB + (size_t)row * DM)
                    : (row < 32) ? (WC + (size_t)(row - 16) * DM)
                                 : (WD1 + (size_t)(row - 32) * DM);
    const float4* p = (const float4*)(bp + k0 + q * 8);
    pf0[j - 1] = p[0]; pf1[j - 1] = p[1];
  };
  auto stu_b = [&](int j) {
    int u = tid + j * 256;
    if (u >= 640) return;
    int v = u - 256, row = v >> 2, q = v & 3;
    *(short8*)&Bs[row * 40 + q * 8] = pack8(pf0[j - 1], pf1[j - 1]);
  };

  ldu_a(kbeg); ldu_b(1, kbeg); ldu_b(2, kbeg);
  for (int k0 = kbeg; k0 < kbeg + 128; k0 += 32) {
    stu_a(k0); stu_b(1); stu_b(2);
    __syncthreads();
    if (k0 + 32 < kbeg + 128) { ldu_a(k0 + 32); ldu_b(1, k0 + 32); ldu_b(2, k0 + 32); }
    short8 afr = *(const short8*)&As[(wave * 16 + r16) * 40 + quad * 8];
#pragma unroll
    for (int ni = 0; ni < 6; ni++) {
      short8 bfr = *(const short8*)&Bs[(ni * 16 + r16) * 40 + quad * 8];
      acc[ni] = __builtin_amdgcn_mfma_f32_16x16x32_bf16(afr, bfr, acc[ni], 0, 0, 0);
    }
    __syncthreads();
  }
#pragma unroll
  for (int ni = 0; ni < 6; ni++) {
    int gn = ni * 16 + r16;
#pragma unroll
    for (int r = 0; r < 4; r++) {
      int gm = m0 + wave * 16 + quad * 4 + r;
      atomicAdd(&pall[(size_t)gm * 96 + gn], acc[ni][r]);
    }
  }
}

// ---------------------------------------------------------------------------
// delta: dltT[1024,2048] = softplus(t1 . WD2^T + Dv)^T  (transposed store)
// ---------------------------------------------------------------------------
__global__ __launch_bounds__(256)
void delta_k(const float* __restrict__ t1, const float* __restrict__ WD2,
             const float* __restrict__ Dv, float* __restrict__ dltT) {
  __shared__ short As[64 * 40];
  __shared__ short Bs[64 * 40];
  const int tid  = threadIdx.x;
  const int lane = tid & 63;
  const int wave = tid >> 6;
  const int r16  = lane & 15;
  const int quad = lane >> 4;
  const int m0 = blockIdx.y * 64;
  const int n0 = blockIdx.x * 64;
  const int wm = wave & 1, wn = wave >> 1;
  float4v acc[2][2];
#pragma unroll
  for (int i = 0; i < 2; i++)
#pragma unroll
    for (int j = 0; j < 2; j++) acc[i][j] = (float4v){0.f, 0.f, 0.f, 0.f};
  float4 pf0[2], pf1[2];
  auto ldu = [&](int j, int k0) {
    int u = tid + j * 256;
    const float4* p;
    if (u < 256) { int row = u >> 2, q = u & 3;
      p = (const float4*)(t1 + (size_t)(m0 + row) * 96 + k0 + q * 8);
    } else { int v = u - 256; int row = v >> 2, q = v & 3;
      p = (const float4*)(WD2 + (size_t)(n0 + row) * DD + k0 + q * 8);
    }
    pf0[j] = p[0]; pf1[j] = p[1];
  };
  auto stu = [&](int j) {
    int u = tid + j * 256;
    short8 s = pack8(pf0[j], pf1[j]);
    if (u < 256) { int row = u >> 2, q = u & 3; *(short8*)&As[row * 40 + q * 8] = s; }
    else { int v = u - 256; int row = v >> 2, q = v & 3; *(short8*)&Bs[row * 40 + q * 8] = s; }
  };
  ldu(0, 0); ldu(1, 0);
  for (int k0 = 0; k0 < DD; k0 += 32) {
    stu(0); stu(1);
    __syncthreads();
    if (k0 + 32 < DD) { ldu(0, k0 + 32); ldu(1, k0 + 32); }
    short8 afr[2], bfr[2];
#pragma unroll
    for (int mi = 0; mi < 2; mi++)
      afr[mi] = *(const short8*)&As[(wm * 32 + mi * 16 + r16) * 40 + quad * 8];
#pragma unroll
    for (int ni = 0; ni < 2; ni++)
      bfr[ni] = *(const short8*)&Bs[(wn * 32 + ni * 16 + r16) * 40 + quad * 8];
#pragma unroll
    for (int mi = 0; mi < 2; mi++)
#pragma unroll
      for (int ni = 0; ni < 2; ni++)
        acc[mi][ni] = __builtin_amdgcn_mfma_f32_16x16x32_bf16(afr[mi], bfr[ni], acc[mi][ni], 0, 0, 0);
    __syncthreads();
  }
#pragma unroll
  for (int mi = 0; mi < 2; mi++)
#pragma unroll
    for (int ni = 0; ni < 2; ni++) {
      int gn = n0 + wn * 32 + ni * 16 + r16;
      float dvn = Dv[gn];
#pragma unroll
      for (int r = 0; r < 4; r++) {
        int gm = m0 + wm * 32 + mi * 16 + quad * 4 + r;
        float v = acc[mi][ni][r] + dvn;
        v = fmaxf(v, 0.f) + log1pf(expf(-fabsf(v)));   // stable softplus
        dltT[(size_t)gn * NROW + gm] = v;              // transposed, 16B runs
      }
    }
}

// ---------------------------------------------------------------------------
// Fused selective scan, transposed operands, quad-batched loads (R12-proven).
// sout stored bf16 (RNE at store == gemm2's staging convert).
// ---------------------------------------------------------------------------
__global__ __launch_bounds__(256)
void scan_fused_k(const float* __restrict__ xt, const float* __restrict__ dltT,
                  const float* __restrict__ pall, const float* __restrict__ A,
                  const float* __restrict__ Dv, const short* __restrict__ gt,
                  short* __restrict__ soutb) {
  __shared__ float Pl[SC][DS][SDP];
  __shared__ float Hl[SC][DS][SDP];
  const int blk = blockIdx.x;
  const int b   = blk >> 8;                // DM/SD = 256 blocks per batch
  const int d0  = (blk & 255) * SD;
  const int dd  = threadIdx.x & (SD - 1);
  const int c   = threadIdx.x >> 2;        // 0..63
  const int d   = d0 + dd;

  float e[DS];
#pragma unroll
  for (int s = 0; s < DS; s++) e[s] = expf(-A[d * DS + s]);
  const int nbase = b * L_ + c * SLC;
  const float* xrow = xt   + (size_t)d * NROW;
  const float* drow = dltT + (size_t)d * NROW;
  const short* grow = gt   + (size_t)d * NROW;

  // ---- phase A: local chunk scan, quad-batched ------------------------
  float h[DS], p[DS];
#pragma unroll
  for (int s = 0; s < DS; s++) { h[s] = 0.f; p[s] = 1.f; }
#pragma unroll
  for (int q = 0; q < SLC / 4; q++) {
    const int n = nbase + q * 4;
    float4 x4 = *(const float4*)(xrow + n);
    float4 d4 = *(const float4*)(drow + n);
    float4 bq[4][4];
#pragma unroll
    for (int t = 0; t < 4; t++) {
      const float4* pp = (const float4*)(pall + (size_t)(n + t) * 96);
      bq[t][0] = pp[0]; bq[t][1] = pp[1]; bq[t][2] = pp[2]; bq[t][3] = pp[3];
    }
#pragma unroll
    for (int t = 0; t < 4; t++) {
      float dl = (&d4.x)[t], xv = (&x4.x)[t];
      float dx = dl * xv;
      float bmv[DS] = { bq[t][0].x, bq[t][0].y, bq[t][0].z, bq[t][0].w,
                        bq[t][1].x, bq[t][1].y, bq[t][1].z, bq[t][1].w,
                        bq[t][2].x, bq[t][2].y, bq[t][2].z, bq[t][2].w,
                        bq[t][3].x, bq[t][3].y, bq[t][3].z, bq[t][3].w };
#pragma unroll
      for (int s = 0; s < DS; s++) {
        float a_ = e[s] * dl;
        h[s] = a_ * h[s] + bmv[s] * dx;
        p[s] *= a_;
      }
    }
  }
#pragma unroll
  for (int s = 0; s < DS; s++) { Pl[c][s][dd] = p[s]; Hl[c][s][dd] = h[s]; }
  __syncthreads();

  // ---- phase B: serial combine of 64 chunk carries --------------------
  if (threadIdx.x < DS * SD) {
    int s2  = threadIdx.x >> 2;
    int dd2 = threadIdx.x & (SD - 1);
    float H = 0.f;
    for (int c2 = 0; c2 < SC; c2++) {
      float pp = Pl[c2][s2][dd2];
      float hh = Hl[c2][s2][dd2];
      Pl[c2][s2][dd2] = H;
      H = pp * H + hh;
    }
  }
  __syncthreads();

  // ---- phase C: replay with fused epilogue, quad-batched --------------
#pragma unroll
  for (int s = 0; s < DS; s++) h[s] = Pl[c][s][dd];
  float Dd = Dv[d];
#pragma unroll
  for (int q = 0; q < SLC / 4; q++) {
    const int n = nbase + q * 4;
    float4 x4 = *(const float4*)(xrow + n);
    float4 d4 = *(const float4*)(drow + n);
    short4v g4 = *(const short4v*)(grow + n);
    float4 bq[4][4], cq[4][4];
#pragma unroll
    for (int t = 0; t < 4; t++) {
      const float4* pp = (const float4*)(pall + (size_t)(n + t) * 96);
      bq[t][0] = pp[0]; bq[t][1] = pp[1]; bq[t][2] = pp[2]; bq[t][3] = pp[3];
      cq[t][0] = pp[4]; cq[t][1] = pp[5]; cq[t][2] = pp[6]; cq[t][3] = pp[7];
    }
#pragma unroll
    for (int t = 0; t < 4; t++) {
      float dl = (&d4.x)[t], xv = (&x4.x)[t];
      float dx = dl * xv;
      float bmv[DS] = { bq[t][0].x, bq[t][0].y, bq[t][0].z, bq[t][0].w,
                        bq[t][1].x, bq[t][1].y, bq[t][1].z, bq[t][1].w,
                        bq[t][2].x, bq[t][2].y, bq[t][2].z, bq[t][2].w,
                        bq[t][3].x, bq[t][3].y, bq[t][3].z, bq[t][3].w };
      float cmv[DS] = { cq[t][0].x, cq[t][0].y, cq[t][0].z, cq[t][0].w,
                        cq[t][1].x, cq[t][1].y, cq[t][1].z, cq[t][1].w,
                        cq[t][2].x, cq[t][2].y, cq[t][2].z, cq[t][2].w,
                        cq[t][3].x, cq[t][3].y, cq[t][3].z, cq[t][3].w };
      float y = 0.f;
#pragma unroll
      for (int s = 0; s < DS; s++) {
        h[s] = e[s] * dl * h[s] + bmv[s] * dx;
        y += h[s] * cmv[s];
      }
      y += Dd * xv;
      float g = bf2f(g4[t]);
      soutb[(size_t)(n + t) * DM + d] = f2bf1(y * silu_f(g));
    }
  }
}

// ---------------------------------------------------------------------------
// GEMM2: out[2048,512] = sout(bf16)[2048,1024] . Wout[512,1024]^T
// BM=64, BN=32 -> 512 blocks. 256 thr = 4 waves (2x2), wave tile 32x16.
// ---------------------------------------------------------------------------
__global__ __launch_bounds__(256)
void gemm2_k(const short* __restrict__ soutb, const float* __restrict__ Wout,
             float* __restrict__ out) {
  __shared__ short As[64 * 40];
  __shared__ short Bs[32 * 40];
  const int tid  = threadIdx.x;
  const int lane = tid & 63;
  const int wave = tid >> 6;
  const int r16  = lane & 15;
  const int quad = lane >> 4;
  const int m0 = blockIdx.y * 64;
  const int n0 = blockIdx.x * 32;
  const int wm = wave & 1, wn = wave >> 1;
  float4v acc[2];
  acc[0] = (float4v){0.f, 0.f, 0.f, 0.f};
  acc[1] = (float4v){0.f, 0.f, 0.f, 0.f};
  short8 pa;
  float4 pf0, pf1;
  auto ldu = [&](int k0) {
    {
      int row = tid >> 2, q = tid & 3;
      pa = *(const short8*)(soutb + (size_t)(m0 + row) * DM + k0 + q * 8);
    }
    if (tid < 128) {
      int row = tid >> 2, q = tid & 3;
      const float4* p = (const float4*)(Wout + (size_t)(n0 + row) * DM + k0 + q * 8);
      pf0 = p[0]; pf1 = p[1];
    }
  };
  auto stu = [&]() {
    { int row = tid >> 2, q = tid & 3; *(short8*)&As[row * 40 + q * 8] = pa; }
    if (tid < 128) { int row = tid >> 2, q = tid & 3; *(short8*)&Bs[row * 40 + q * 8] = pack8(pf0, pf1); }
  };
  ldu(0);
  for (int k0 = 0; k0 < DM; k0 += 32) {
    stu();
    __syncthreads();
    if (k0 + 32 < DM) ldu(k0 + 32);
    short8 afr[2], bfr;
    afr[0] = *(const short8*)&As[(wm * 32 + r16) * 40 + quad * 8];
    afr[1] = *(const short8*)&As[(wm * 32 + 16 + r16) * 40 + quad * 8];
    bfr    = *(const short8*)&Bs[(wn * 16 + r16) * 40 + quad * 8];
    acc[0] = __builtin_amdgcn_mfma_f32_16x16x32_bf16(afr[0], bfr, acc[0], 0, 0, 0);
    acc[1] = __builtin_amdgcn_mfma_f32_16x16x32_bf16(afr[1], bfr, acc[1], 0, 0, 0);
    __syncthreads();
  }
#pragma unroll
  for (int mi = 0; mi < 2; mi++)
#pragma unroll
    for (int r = 0; r < 4; r++)
      out[(size_t)(m0 + wm * 32 + mi * 16 + quad * 4 + r) * DIN + n0 + wn * 16 + r16] = acc[mi][r];
}

// ---------------------------------------------------------------------------
extern "C" void kernel_launch(void* const* d_in, const int* in_sizes, int n_in,
                              void* d_out, int out_size, void* d_ws, size_t ws_size,
                              hipStream_t stream) {
  const float* seq  = (const float*)d_in[0];
  const float* Win  = (const float*)d_in[1];
  const float* Wout = (const float*)d_in[2];
  const float* WB   = (const float*)d_in[3];
  const float* WC   = (const float*)d_in[4];
  const float* WD1  = (const float*)d_in[5];
  const float* WD2  = (const float*)d_in[6];
  const float* cw   = (const float*)d_in[7];
  const float* cb   = (const float*)d_in[8];
  const float* A    = (const float*)d_in[9];
  const float* Dv   = (const float*)d_in[10];
  float* out = (float*)d_out;

  float* ws = (float*)d_ws;
  __hip_bfloat16* ab = (__hip_bfloat16*)ws;       // 2048*2048 bf16
  float* xt   = ws   + 2097152;                   // 1024*2048 f32  (x transposed)
  short* gt   = (short*)(xt + 2097152);           // 1024*2048 bf16 (gate transposed)
  float* dltT = (float*)(gt + 2097152);           // 1024*2048 f32  (delta transposed)
  float* pall = dltT + 2097152;                   // 2048*96 f32 (Bm|Cm|t1)
  short* soutb = (short*)(pall + 196608);         // 2048*1024 bf16
  // total ~35 MB (proven budget 47)
  float* t1   = pall + 32;                        // t1 rows at col 32 (ld 96)

  gemm1_k<<<dim3(32, 32), 256, 0, stream>>>(seq, Win, ab, pall);
  convproj_k<<<1280, 256, 0, stream>>>(ab, cw, cb, WB, WC, WD1, xt, gt, pall);
  delta_k<<<dim3(16, 32), 256, 0, stream>>>(t1, WD2, Dv, dltT);
  scan_fused_k<<<B_ * (DM / SD), 256, 0, stream>>>(xt, dltT, pall, A, Dv, gt, soutb);
  gemm2_k<<<dim3(16, 32), 256, 0, stream>>>(soutb, Wout, out);
}